// Round 4
// baseline (720.106 us; speedup 1.0000x reference)
//
#include <hip/hip_runtime.h>
#include <math.h>

// CapsLayer dynamic routing, MI355X fp32.
// x: [64, 2048, 8]  W: [2048, 32, 8, 16]  out: [64, 32, 16]
// Never materialize u_hat (256 MB); recompute per routing pass.
// R4: R2 structure + (a) explicit register double-buffer prefetch of W
// (fixes compiler-serialized global loads seen in R2/R3, VGPR 36/60),
// (b) algebraic removal of the logit workspace: pass-2 logits
// u.v0 + u.v1 == u.(v0+v1), so pass 2 is MODE1 with vin = v0+v1,
// (c) reduce_squash split over 512 blocks with 8-deep MLP.

#define B_TOT 64
#define I_TOT 2048
#define NC    32
#define EV    16
#define OD    (NC*EV)      // 512
#define BC    8            // batch rows per block
#define ICH   16           // i's per block
#define NIC   (I_TOT/ICH)  // 128

__device__ __forceinline__ void fma4(float4& acc, float a, const float4& w) {
    acc.x = fmaf(a, w.x, acc.x);
    acc.y = fmaf(a, w.y, acc.y);
    acc.z = fmaf(a, w.z, acc.z);
    acc.w = fmaf(a, w.w, acc.w);
}

// MODE 0: c uniform (iter 0)          -> P partials
// MODE 1: a = u.vin, c = softmax(a)   -> P partials   (used for pass 1 AND 2)
template <int MODE>
__global__ __launch_bounds__(256, 4)
void route_pass(const float* __restrict__ x, const float* __restrict__ W,
                float* __restrict__ P, const float* __restrict__ vin)
{
    __shared__ __align__(16) float xl[BC * ICH * 8];      // 4 KB
    __shared__ float wsum[2][4][BC];                      // 256 B double-buffered

    const int t  = threadIdx.x;
    const int ic = blockIdx.x & (NIC - 1);   // XCD = f(ic): bc-siblings share L2
    const int bc = blockIdx.x >> 7;          // 0..7
    const int b0 = bc * BC;
    const int i0 = ic * ICH;
    const int eq = t & 3;          // e quarter
    const int bh = (t >> 2) & 1;   // b half (4 rows each)
    const int n  = t >> 3;         // capsule 0..31
    const int w  = t >> 6;         // wave 0..3

    // ---- stage x[b0..b0+7][i0..i0+15][0..7] (1024 floats) ----
    {
        const int f = t * 4, row = t >> 5, off = f & 127;
        *(float4*)&xl[row * 128 + off] =
            *(const float4*)&x[((size_t)(b0 + row) * I_TOT + i0) * 8 + off];
    }

    float4 vr[4];
    if (MODE == 1) {
        #pragma unroll
        for (int q = 0; q < 4; ++q)
            vr[q] = *(const float4*)&vin[(size_t)(b0 + bh * 4 + q) * OD + n * EV + eq * 4];
    }
    __syncthreads();

    float4 sacc[4];
    #pragma unroll
    for (int q = 0; q < 4; ++q) sacc[q] = make_float4(0.f, 0.f, 0.f, 0.f);

    const float* Wb = W + (size_t)i0 * 4096 + n * 128 + eq * 4;

    // ---- register double-buffer for W: prefetch ii+1 while computing ii ----
    float4 wreg[2][8];
    #pragma unroll
    for (int d = 0; d < 8; ++d)
        wreg[0][d] = *(const float4*)&Wb[d * 16];

    #pragma unroll
    for (int ii = 0; ii < ICH; ++ii) {
        const int cur = ii & 1, nxt = cur ^ 1;
        if (ii + 1 < ICH) {
            #pragma unroll
            for (int d = 0; d < 8; ++d)
                wreg[nxt][d] = *(const float4*)&Wb[(ii + 1) * 4096 + d * 16];
        }

        if (MODE == 0) {
            // fold u straight into sacc (c uniform; 1/32 applied in reduce)
            #pragma unroll
            for (int q = 0; q < 4; ++q) {
                const int bl = bh * 4 + q;
                float4 xa = *(float4*)&xl[bl * 128 + ii * 8];
                float4 xb = *(float4*)&xl[bl * 128 + ii * 8 + 4];
                fma4(sacc[q], xa.x, wreg[cur][0]); fma4(sacc[q], xa.y, wreg[cur][1]);
                fma4(sacc[q], xa.z, wreg[cur][2]); fma4(sacc[q], xa.w, wreg[cur][3]);
                fma4(sacc[q], xb.x, wreg[cur][4]); fma4(sacc[q], xb.y, wreg[cur][5]);
                fma4(sacc[q], xb.z, wreg[cur][6]); fma4(sacc[q], xb.w, wreg[cur][7]);
            }
        } else {
            float4 u[4];
            #pragma unroll
            for (int q = 0; q < 4; ++q) {
                const int bl = bh * 4 + q;
                float4 xa = *(float4*)&xl[bl * 128 + ii * 8];
                float4 xb = *(float4*)&xl[bl * 128 + ii * 8 + 4];
                float4 uu = make_float4(0.f, 0.f, 0.f, 0.f);
                fma4(uu, xa.x, wreg[cur][0]); fma4(uu, xa.y, wreg[cur][1]);
                fma4(uu, xa.z, wreg[cur][2]); fma4(uu, xa.w, wreg[cur][3]);
                fma4(uu, xb.x, wreg[cur][4]); fma4(uu, xb.y, wreg[cur][5]);
                fma4(uu, xb.z, wreg[cur][6]); fma4(uu, xb.w, wreg[cur][7]);
                u[q] = uu;
            }
            // logits: dot over 4 e in-thread + shfl over eq bits (full 16-e dot)
            float e[4];
            #pragma unroll
            for (int q = 0; q < 4; ++q) {
                float ap = u[q].x * vr[q].x + u[q].y * vr[q].y
                         + u[q].z * vr[q].z + u[q].w * vr[q].w;
                ap += __shfl_xor(ap, 1, 64);
                ap += __shfl_xor(ap, 2, 64);
                e[q] = __expf(ap);
            }
            // wave-partial softmax denominator over this wave's 8 n's
            float p[4];
            #pragma unroll
            for (int q = 0; q < 4; ++q) {
                float pp = e[q];
                pp += __shfl_xor(pp, 8, 64);
                pp += __shfl_xor(pp, 16, 64);
                pp += __shfl_xor(pp, 32, 64);
                p[q] = pp;
            }
            if (eq == 0) {
                #pragma unroll
                for (int q = 0; q < 4; ++q)
                    wsum[cur][w][bh * 4 + q] = p[q];
            }
            __syncthreads();   // only barrier per ii (wsum double-buffered)
            #pragma unroll
            for (int q = 0; q < 4; ++q) {
                const int bl = bh * 4 + q;
                float s = wsum[cur][0][bl] + wsum[cur][1][bl]
                        + wsum[cur][2][bl] + wsum[cur][3][bl];
                fma4(sacc[q], e[q] / s, u[q]);
            }
        }
    }

    // ---- partials: P[ic][b][o] (coalesced float4) ----
    #pragma unroll
    for (int q = 0; q < 4; ++q)
        *(float4*)&P[((size_t)ic * B_TOT + b0 + bh * 4 + q) * OD + n * EV + eq * 4] = sacc[q];
}

// Reduce partials over NIC chunks + squash. grid = 64 b x 8 o-groups, 64 thr.
// dst[b*512+o] = squash(pre * sum_ic P)[o] + (addv ? addv[b*512+o] : 0)
__global__ __launch_bounds__(64)
void reduce_squash(const float* __restrict__ P, float* __restrict__ dst,
                   float pre, const float* __restrict__ addv)
{
    const int b = blockIdx.x >> 3, og = blockIdx.x & 7, t = threadIdx.x;
    const int o = og * 64 + t;
    float s0 = 0.f, s1 = 0.f, s2 = 0.f, s3 = 0.f;
    float s4 = 0.f, s5 = 0.f, s6 = 0.f, s7 = 0.f;
    for (int ic = 0; ic < NIC; ic += 8) {
        s0 += P[((size_t)(ic + 0) * B_TOT + b) * OD + o];
        s1 += P[((size_t)(ic + 1) * B_TOT + b) * OD + o];
        s2 += P[((size_t)(ic + 2) * B_TOT + b) * OD + o];
        s3 += P[((size_t)(ic + 3) * B_TOT + b) * OD + o];
        s4 += P[((size_t)(ic + 4) * B_TOT + b) * OD + o];
        s5 += P[((size_t)(ic + 5) * B_TOT + b) * OD + o];
        s6 += P[((size_t)(ic + 6) * B_TOT + b) * OD + o];
        s7 += P[((size_t)(ic + 7) * B_TOT + b) * OD + o];
    }
    float s = (((s0 + s1) + (s2 + s3)) + ((s4 + s5) + (s6 + s7))) * pre;
    // squared norm over e (o = n*16 + e; e bits are t&15)
    float q = s * s;
    q += __shfl_xor(q, 1, 64);
    q += __shfl_xor(q, 2, 64);
    q += __shfl_xor(q, 4, 64);
    q += __shfl_xor(q, 8, 64);
    float sc = q / ((1.0f + q) * sqrtf(q));
    float r = s * sc;
    if (addv) r += addv[(size_t)b * OD + o];
    dst[(size_t)b * OD + o] = r;
}

extern "C" void kernel_launch(void* const* d_in, const int* in_sizes, int n_in,
                              void* d_out, int out_size, void* d_ws, size_t ws_size,
                              hipStream_t stream) {
    const float* x = (const float*)d_in[0];
    const float* W = (const float*)d_in[1];
    float* out = (float*)d_out;

    char* ws = (char*)d_ws;
    float* P    = (float*)ws;                               // 128*64*512*4 = 16 MB
    float* v0   = (float*)(ws + (size_t)16 * 1024 * 1024);  // 128 KB
    float* vsum = v0 + B_TOT * OD;                          // 128 KB

    dim3 grid(8 * NIC), blk(256);   // 1024 blocks, 4 per CU

    // pass 0: c uniform (1/32 folded into reduce pre-scale) -> v0
    route_pass<0><<<grid, blk, 0, stream>>>(x, W, P, nullptr);
    reduce_squash<<<B_TOT * 8, 64, 0, stream>>>(P, v0, 1.0f / 32.0f, nullptr);
    // pass 1: c = softmax(u.v0) -> v1; write vsum = v0 + v1
    route_pass<1><<<grid, blk, 0, stream>>>(x, W, P, v0);
    reduce_squash<<<B_TOT * 8, 64, 0, stream>>>(P, vsum, 1.0f, v0);
    // pass 2: logits = u.v0 + u.v1 = u.(v0+v1); c = softmax -> out
    route_pass<1><<<grid, blk, 0, stream>>>(x, W, P, vsum);
    reduce_squash<<<B_TOT * 8, 64, 0, stream>>>(P, out, 1.0f, nullptr);
}

// Round 5
// 709.549 us; speedup vs baseline: 1.0149x; 1.0149x over previous
//
#include <hip/hip_runtime.h>
#include <math.h>

// CapsLayer dynamic routing, MI355X fp32.
// x: [64, 2048, 8]  W: [2048, 32, 8, 16]  out: [64, 32, 16]
// Never materialize u_hat (256 MB); recompute per routing pass.
// R5: R2 body unchanged (36 VGPR, no spill — R4's register pipelining spilled
// 2KB/thread to scratch). R2 was latency-bound: 8.7 B/cyc/CU vs 56 B/cyc L2
// ceiling, Little's law with only 4 blocks/CU. Fix = concurrency: ICH 16->8,
// grid 1024->2048 = 8 blocks/CU = 32 waves/CU (occupancy 100%),
// __launch_bounds__(256,8). Pass-2 logits still u.(v0+v1) (no aws).

#define B_TOT 64
#define I_TOT 2048
#define NC    32
#define EV    16
#define OD    (NC*EV)      // 512
#define BC    8            // batch rows per block
#define ICH   8            // i's per block
#define NIC   (I_TOT/ICH)  // 256

__device__ __forceinline__ void fma4(float4& acc, float a, const float4& w) {
    acc.x = fmaf(a, w.x, acc.x);
    acc.y = fmaf(a, w.y, acc.y);
    acc.z = fmaf(a, w.z, acc.z);
    acc.w = fmaf(a, w.w, acc.w);
}

// MODE 0: c uniform (iter 0)          -> P partials
// MODE 1: a = u.vin, c = softmax(a)   -> P partials   (used for pass 1 AND 2)
template <int MODE>
__global__ __launch_bounds__(256, 8)
void route_pass(const float* __restrict__ x, const float* __restrict__ W,
                float* __restrict__ P, const float* __restrict__ vin)
{
    __shared__ __align__(16) float xl[BC * ICH * 8];      // 2 KB
    __shared__ float wsum[2][4][BC];                      // 256 B double-buffered

    const int t  = threadIdx.x;
    const int ic = blockIdx.x & (NIC - 1);   // XCD = f(ic): bc-siblings share L2
    const int bc = blockIdx.x >> 8;          // 0..7
    const int b0 = bc * BC;
    const int i0 = ic * ICH;
    const int eq = t & 3;          // e quarter
    const int bh = (t >> 2) & 1;   // b half (4 rows each)
    const int n  = t >> 3;         // capsule 0..31
    const int w  = t >> 6;         // wave 0..3

    // ---- stage x[b0..b0+7][i0..i0+7][0..7] (512 floats) ----
    if (t < 128) {
        const int row = t >> 4, off = (t & 15) * 4;
        *(float4*)&xl[row * 64 + off] =
            *(const float4*)&x[((size_t)(b0 + row) * I_TOT + i0) * 8 + off];
    }

    float4 vr[4];
    if (MODE == 1) {
        #pragma unroll
        for (int q = 0; q < 4; ++q)
            vr[q] = *(const float4*)&vin[(size_t)(b0 + bh * 4 + q) * OD + n * EV + eq * 4];
    }
    __syncthreads();

    float4 sacc[4];
    #pragma unroll
    for (int q = 0; q < 4; ++q) sacc[q] = make_float4(0.f, 0.f, 0.f, 0.f);

    const float* Wb = W + (size_t)i0 * 4096 + n * 128 + eq * 4;

    for (int ii = 0; ii < ICH; ++ii) {
        // ---- this thread's W fragment (8 x float4, one clause) ----
        float4 wr[8];
        #pragma unroll
        for (int d = 0; d < 8; ++d)
            wr[d] = *(const float4*)&Wb[ii * 4096 + d * 16];

        // ---- u for 4 batch rows ----
        float4 u[4];
        #pragma unroll
        for (int q = 0; q < 4; ++q) {
            const int bl = bh * 4 + q;
            float4 xa = *(float4*)&xl[bl * 64 + ii * 8];
            float4 xb = *(float4*)&xl[bl * 64 + ii * 8 + 4];
            float4 uu = make_float4(0.f, 0.f, 0.f, 0.f);
            fma4(uu, xa.x, wr[0]); fma4(uu, xa.y, wr[1]);
            fma4(uu, xa.z, wr[2]); fma4(uu, xa.w, wr[3]);
            fma4(uu, xb.x, wr[4]); fma4(uu, xb.y, wr[5]);
            fma4(uu, xb.z, wr[6]); fma4(uu, xb.w, wr[7]);
            u[q] = uu;
        }

        if (MODE == 0) {
            #pragma unroll
            for (int q = 0; q < 4; ++q) {
                sacc[q].x += u[q].x; sacc[q].y += u[q].y;
                sacc[q].z += u[q].z; sacc[q].w += u[q].w;
            }
        } else {
            // logits: dot over 4 e in-thread + shfl over eq bits (full 16-e dot)
            float e[4];
            #pragma unroll
            for (int q = 0; q < 4; ++q) {
                float ap = u[q].x * vr[q].x + u[q].y * vr[q].y
                         + u[q].z * vr[q].z + u[q].w * vr[q].w;
                ap += __shfl_xor(ap, 1, 64);
                ap += __shfl_xor(ap, 2, 64);
                e[q] = __expf(ap);
            }
            // wave-partial softmax denominator over this wave's 8 n's
            float p[4];
            #pragma unroll
            for (int q = 0; q < 4; ++q) {
                float pp = e[q];
                pp += __shfl_xor(pp, 8, 64);
                pp += __shfl_xor(pp, 16, 64);
                pp += __shfl_xor(pp, 32, 64);
                p[q] = pp;
            }
            if (eq == 0) {
                #pragma unroll
                for (int q = 0; q < 4; ++q)
                    wsum[ii & 1][w][bh * 4 + q] = p[q];
            }
            __syncthreads();   // only barrier per ii (wsum double-buffered)
            #pragma unroll
            for (int q = 0; q < 4; ++q) {
                const int bl = bh * 4 + q;
                float s = wsum[ii & 1][0][bl] + wsum[ii & 1][1][bl]
                        + wsum[ii & 1][2][bl] + wsum[ii & 1][3][bl];
                fma4(sacc[q], e[q] / s, u[q]);
            }
        }
    }

    // ---- partials: P[ic][b][o] (coalesced float4) ----
    #pragma unroll
    for (int q = 0; q < 4; ++q)
        *(float4*)&P[((size_t)ic * B_TOT + b0 + bh * 4 + q) * OD + n * EV + eq * 4] = sacc[q];
}

// Reduce partials over NIC chunks + squash. grid = 64 b x 8 o-groups, 64 thr.
// dst[b*512+o] = squash(pre * sum_ic P)[o] + (addv ? addv[b*512+o] : 0)
__global__ __launch_bounds__(64)
void reduce_squash(const float* __restrict__ P, float* __restrict__ dst,
                   float pre, const float* __restrict__ addv)
{
    const int b = blockIdx.x >> 3, og = blockIdx.x & 7, t = threadIdx.x;
    const int o = og * 64 + t;
    float s0 = 0.f, s1 = 0.f, s2 = 0.f, s3 = 0.f;
    float s4 = 0.f, s5 = 0.f, s6 = 0.f, s7 = 0.f;
    for (int ic = 0; ic < NIC; ic += 8) {
        s0 += P[((size_t)(ic + 0) * B_TOT + b) * OD + o];
        s1 += P[((size_t)(ic + 1) * B_TOT + b) * OD + o];
        s2 += P[((size_t)(ic + 2) * B_TOT + b) * OD + o];
        s3 += P[((size_t)(ic + 3) * B_TOT + b) * OD + o];
        s4 += P[((size_t)(ic + 4) * B_TOT + b) * OD + o];
        s5 += P[((size_t)(ic + 5) * B_TOT + b) * OD + o];
        s6 += P[((size_t)(ic + 6) * B_TOT + b) * OD + o];
        s7 += P[((size_t)(ic + 7) * B_TOT + b) * OD + o];
    }
    float s = (((s0 + s1) + (s2 + s3)) + ((s4 + s5) + (s6 + s7))) * pre;
    // squared norm over e (o = n*16 + e; e bits are t&15)
    float q = s * s;
    q += __shfl_xor(q, 1, 64);
    q += __shfl_xor(q, 2, 64);
    q += __shfl_xor(q, 4, 64);
    q += __shfl_xor(q, 8, 64);
    float sc = q / ((1.0f + q) * sqrtf(q));
    float r = s * sc;
    if (addv) r += addv[(size_t)b * OD + o];
    dst[(size_t)b * OD + o] = r;
}

extern "C" void kernel_launch(void* const* d_in, const int* in_sizes, int n_in,
                              void* d_out, int out_size, void* d_ws, size_t ws_size,
                              hipStream_t stream) {
    const float* x = (const float*)d_in[0];
    const float* W = (const float*)d_in[1];
    float* out = (float*)d_out;

    char* ws = (char*)d_ws;
    float* P    = (float*)ws;                               // 256*64*512*4 = 32 MB
    float* v0   = (float*)(ws + (size_t)32 * 1024 * 1024);  // 128 KB
    float* vsum = v0 + B_TOT * OD;                          // 128 KB

    dim3 grid(8 * NIC), blk(256);   // 2048 blocks = 8 per CU (occupancy 100%)

    // pass 0: c uniform (1/32 folded into reduce pre-scale) -> v0
    route_pass<0><<<grid, blk, 0, stream>>>(x, W, P, nullptr);
    reduce_squash<<<B_TOT * 8, 64, 0, stream>>>(P, v0, 1.0f / 32.0f, nullptr);
    // pass 1: c = softmax(u.v0) -> v1; write vsum = v0 + v1
    route_pass<1><<<grid, blk, 0, stream>>>(x, W, P, v0);
    reduce_squash<<<B_TOT * 8, 64, 0, stream>>>(P, vsum, 1.0f, v0);
    // pass 2: logits = u.v0 + u.v1 = u.(v0+v1); c = softmax -> out
    route_pass<1><<<grid, blk, 0, stream>>>(x, W, P, vsum);
    reduce_squash<<<B_TOT * 8, 64, 0, stream>>>(P, out, 1.0f, nullptr);
}

// Round 6
// 239.828 us; speedup vs baseline: 3.0026x; 2.9586x over previous
//
#include <hip/hip_runtime.h>
#include <math.h>

// CapsLayer dynamic routing, MI355X fp32.
// x: [64, 2048, 8]  W: [2048, 32, 8, 16]  out: [64, 32, 16]
// R6: LDS-resident double-buffered W tiles. Lessons: R4/R5 proved forced
// occupancy/pipelining spills (needs ~60+ VGPR); R2 proved per-thread global
// W streaming is latency-bound. Now: BC=16 rows/block (2x W reuse vs R2),
// ICH=16 i/block (P stays 16 MB), W tile 16.5 KB padded, double-buffered in
// LDS, prefetched 4 float4/thread per ii with a full compute body to hide
// latency. ONE barrier per ii (covers W-dbuf swap + softmax exchange, both
// double-buffered). grid 512 = 2 blocks/CU, __launch_bounds__(256,2) ->
// 256 VGPR budget (~175 used, no spill). Pass-2 logits = u.(v0+v1), no aws.

#define B_TOT 64
#define I_TOT 2048
#define NC    32
#define EV    16
#define OD    (NC*EV)      // 512
#define BC    16           // batch rows per block
#define ICH   16           // i's per block
#define NIC   (I_TOT/ICH)  // 128
#define WPAD  132          // padded floats per capsule row (128 + 4)
#define WTILE (NC*WPAD)    // 4224 floats per i-tile

__device__ __forceinline__ void fma4(float4& acc, float a, const float4& w) {
    acc.x = fmaf(a, w.x, acc.x);
    acc.y = fmaf(a, w.y, acc.y);
    acc.z = fmaf(a, w.z, acc.z);
    acc.w = fmaf(a, w.w, acc.w);
}
__device__ __forceinline__ float dot4(const float4& a, const float4& b) {
    return a.x*b.x + a.y*b.y + a.z*b.z + a.w*b.w;
}

// MODE 0: c uniform (iter 0)          -> P partials
// MODE 1: a = u.vin, c = softmax(a)   -> P partials   (pass 1 AND pass 2)
template <int MODE>
__global__ __launch_bounds__(256, 2)
void route_pass(const float* __restrict__ x, const float* __restrict__ W,
                float* __restrict__ P, const float* __restrict__ vin)
{
    __shared__ __align__(16) float Wl[2 * WTILE];        // 33 KB (dbuf)
    __shared__ __align__(16) float xl[BC * ICH * 8];     // 8 KB
    __shared__ __align__(16) float wsum2[2][4][BC];      // 512 B (dbuf)

    const int t  = threadIdx.x;
    const int eq = t & 3;          // e quarter (4 e's)
    const int bh = (t >> 2) & 1;   // row half (8 rows each)
    const int n  = t >> 3;         // capsule 0..31 (wave = 8 n's)
    const int w  = t >> 6;         // wave 0..3

    const int ic = blockIdx.x & (NIC - 1);   // XCD = f(ic): bc-siblings share L2
    const int bc = blockIdx.x >> 7;          // 0..3
    const int b0 = bc * BC;
    const int i0 = ic * ICH;

    // ---- stage x[b0..b0+15][i0..i0+15][0..7] (2048 floats, contiguous rows) ----
    #pragma unroll
    for (int j = 0; j < 2; ++j) {
        const int fl = (t + j * 256) * 4;           // 0..2044
        const int row = fl >> 7, off = fl & 127;
        *(float4*)&xl[fl] =
            *(const float4*)&x[((size_t)(b0 + row) * I_TOT + i0) * 8 + off];
    }
    // ---- stage W tile 0 into Wl[0] (padded rows) ----
    #pragma unroll
    for (int k = 0; k < 4; ++k) {
        const int g = (t + 256 * k) * 4;            // float idx 0..4092
        *(float4*)&Wl[(g >> 7) * WPAD + (g & 127)] =
            *(const float4*)&W[(size_t)i0 * 4096 + g];
    }
    // ---- v fragments for this thread's 8 rows ----
    float4 vr[8];
    if (MODE == 1) {
        #pragma unroll
        for (int q = 0; q < 8; ++q)
            vr[q] = *(const float4*)&vin[(size_t)(b0 + bh * 8 + q) * OD + n * EV + eq * 4];
    }
    __syncthreads();

    float4 sacc[8];
    #pragma unroll
    for (int q = 0; q < 8; ++q) sacc[q] = make_float4(0.f, 0.f, 0.f, 0.f);

    #pragma unroll 1
    for (int ii = 0; ii < ICH; ++ii) {
        const int cur = ii & 1, nxt = cur ^ 1;
        const bool pf = (ii + 1 < ICH);

        // ---- prefetch next W tile into registers (latency hidden by compute) ----
        float4 gw[4];
        if (pf) {
            #pragma unroll
            for (int k = 0; k < 4; ++k)
                gw[k] = *(const float4*)&W[(size_t)(i0 + ii + 1) * 4096 + (t + 256 * k) * 4];
        }

        // ---- this thread's W fragment from LDS ----
        const float* Wc = &Wl[cur * WTILE + n * WPAD + eq * 4];
        float4 wr[8];
        #pragma unroll
        for (int d = 0; d < 8; ++d)
            wr[d] = *(const float4*)&Wc[d * 16];

        // ---- u for 8 rows ----
        float4 u[8];
        #pragma unroll
        for (int q = 0; q < 8; ++q) {
            const float* xp = &xl[(bh * 8 + q) * 128 + ii * 8];
            float4 xa = *(const float4*)xp;
            float4 xb = *(const float4*)(xp + 4);
            float4 uu = make_float4(0.f, 0.f, 0.f, 0.f);
            fma4(uu, xa.x, wr[0]); fma4(uu, xa.y, wr[1]);
            fma4(uu, xa.z, wr[2]); fma4(uu, xa.w, wr[3]);
            fma4(uu, xb.x, wr[4]); fma4(uu, xb.y, wr[5]);
            fma4(uu, xb.z, wr[6]); fma4(uu, xb.w, wr[7]);
            u[q] = uu;
        }

        float e[8];
        if (MODE == 1) {
            // logits: dot over 4 e in-thread + shfl over eq bits -> full 16-e dot
            #pragma unroll
            for (int q = 0; q < 8; ++q) {
                float ap = dot4(u[q], vr[q]);
                ap += __shfl_xor(ap, 1, 64);
                ap += __shfl_xor(ap, 2, 64);
                e[q] = __expf(ap);
            }
            // wave-partial denominator over this wave's 8 n's
            float p[8];
            #pragma unroll
            for (int q = 0; q < 8; ++q) {
                float pp = e[q];
                pp += __shfl_xor(pp, 8, 64);
                pp += __shfl_xor(pp, 16, 64);
                pp += __shfl_xor(pp, 32, 64);
                p[q] = pp;
            }
            if (eq == 0 && (n & 7) == 0) {   // 2 lanes/wave (bh 0,1)
                *(float4*)&wsum2[cur][w][bh * 8]     = make_float4(p[0], p[1], p[2], p[3]);
                *(float4*)&wsum2[cur][w][bh * 8 + 4] = make_float4(p[4], p[5], p[6], p[7]);
            }
        } else {
            #pragma unroll
            for (int q = 0; q < 8; ++q) {
                sacc[q].x += u[q].x; sacc[q].y += u[q].y;
                sacc[q].z += u[q].z; sacc[q].w += u[q].w;
            }
        }

        // ---- store prefetched W tile into the other LDS buffer ----
        if (pf) {
            #pragma unroll
            for (int k = 0; k < 4; ++k) {
                const int g = (t + 256 * k) * 4;
                *(float4*)&Wl[nxt * WTILE + (g >> 7) * WPAD + (g & 127)] = gw[k];
            }
        }
        __syncthreads();   // the ONLY barrier per ii (Wl + wsum2 both dbuf'd)

        if (MODE == 1) {
            // total softmax denominators for this thread's 8 rows
            float4 sA = make_float4(0.f, 0.f, 0.f, 0.f);
            float4 sB = make_float4(0.f, 0.f, 0.f, 0.f);
            #pragma unroll
            for (int wv = 0; wv < 4; ++wv) {
                float4 ta = *(const float4*)&wsum2[cur][wv][bh * 8];
                float4 tb = *(const float4*)&wsum2[cur][wv][bh * 8 + 4];
                sA.x += ta.x; sA.y += ta.y; sA.z += ta.z; sA.w += ta.w;
                sB.x += tb.x; sB.y += tb.y; sB.z += tb.z; sB.w += tb.w;
            }
            float rs[8];
            rs[0] = __builtin_amdgcn_rcpf(sA.x); rs[1] = __builtin_amdgcn_rcpf(sA.y);
            rs[2] = __builtin_amdgcn_rcpf(sA.z); rs[3] = __builtin_amdgcn_rcpf(sA.w);
            rs[4] = __builtin_amdgcn_rcpf(sB.x); rs[5] = __builtin_amdgcn_rcpf(sB.y);
            rs[6] = __builtin_amdgcn_rcpf(sB.z); rs[7] = __builtin_amdgcn_rcpf(sB.w);
            #pragma unroll
            for (int q = 0; q < 8; ++q)
                fma4(sacc[q], e[q] * rs[q], u[q]);
        }
    }

    // ---- partials: P[ic][b][o] (coalesced float4) ----
    #pragma unroll
    for (int q = 0; q < 8; ++q)
        *(float4*)&P[((size_t)ic * B_TOT + b0 + bh * 8 + q) * OD + n * EV + eq * 4] = sacc[q];
}

// Reduce partials over NIC chunks + squash. grid = 64 b x 8 o-groups, 64 thr.
// dst[b*512+o] = squash(pre * sum_ic P)[o] + (addv ? addv[b*512+o] : 0)
__global__ __launch_bounds__(64)
void reduce_squash(const float* __restrict__ P, float* __restrict__ dst,
                   float pre, const float* __restrict__ addv)
{
    const int b = blockIdx.x >> 3, og = blockIdx.x & 7, t = threadIdx.x;
    const int o = og * 64 + t;
    float s0 = 0.f, s1 = 0.f, s2 = 0.f, s3 = 0.f;
    float s4 = 0.f, s5 = 0.f, s6 = 0.f, s7 = 0.f;
    for (int ic = 0; ic < NIC; ic += 8) {
        s0 += P[((size_t)(ic + 0) * B_TOT + b) * OD + o];
        s1 += P[((size_t)(ic + 1) * B_TOT + b) * OD + o];
        s2 += P[((size_t)(ic + 2) * B_TOT + b) * OD + o];
        s3 += P[((size_t)(ic + 3) * B_TOT + b) * OD + o];
        s4 += P[((size_t)(ic + 4) * B_TOT + b) * OD + o];
        s5 += P[((size_t)(ic + 5) * B_TOT + b) * OD + o];
        s6 += P[((size_t)(ic + 6) * B_TOT + b) * OD + o];
        s7 += P[((size_t)(ic + 7) * B_TOT + b) * OD + o];
    }
    float s = (((s0 + s1) + (s2 + s3)) + ((s4 + s5) + (s6 + s7))) * pre;
    // squared norm over e (o = n*16 + e; e bits are t&15)
    float q = s * s;
    q += __shfl_xor(q, 1, 64);
    q += __shfl_xor(q, 2, 64);
    q += __shfl_xor(q, 4, 64);
    q += __shfl_xor(q, 8, 64);
    float sc = q / ((1.0f + q) * sqrtf(q));
    float r = s * sc;
    if (addv) r += addv[(size_t)b * OD + o];
    dst[(size_t)b * OD + o] = r;
}

extern "C" void kernel_launch(void* const* d_in, const int* in_sizes, int n_in,
                              void* d_out, int out_size, void* d_ws, size_t ws_size,
                              hipStream_t stream) {
    const float* x = (const float*)d_in[0];
    const float* W = (const float*)d_in[1];
    float* out = (float*)d_out;

    char* ws = (char*)d_ws;
    float* P    = (float*)ws;                               // 128*64*512*4 = 16 MB
    float* v0   = (float*)(ws + (size_t)16 * 1024 * 1024);  // 128 KB
    float* vsum = v0 + B_TOT * OD;                          // 128 KB

    dim3 grid(4 * NIC), blk(256);   // 512 blocks = 2 per CU

    // pass 0: c uniform (1/32 folded into reduce pre-scale) -> v0
    route_pass<0><<<grid, blk, 0, stream>>>(x, W, P, nullptr);
    reduce_squash<<<B_TOT * 8, 64, 0, stream>>>(P, v0, 1.0f / 32.0f, nullptr);
    // pass 1: c = softmax(u.v0) -> v1; write vsum = v0 + v1
    route_pass<1><<<grid, blk, 0, stream>>>(x, W, P, v0);
    reduce_squash<<<B_TOT * 8, 64, 0, stream>>>(P, vsum, 1.0f, v0);
    // pass 2: logits = u.v0 + u.v1 = u.(v0+v1); c = softmax -> out
    route_pass<1><<<grid, blk, 0, stream>>>(x, W, P, vsum);
    reduce_squash<<<B_TOT * 8, 64, 0, stream>>>(P, out, 1.0f, nullptr);
}

// Round 7
// 224.440 us; speedup vs baseline: 3.2085x; 1.0686x over previous
//
#include <hip/hip_runtime.h>
#include <math.h>

// CapsLayer dynamic routing, MI355X fp32.
// x: [64, 2048, 8]  W: [2048, 32, 8, 16]  out: [64, 32, 16]
// R7: kill the LDS-pipe bottleneck (R6: 24 b128/wave-ii, LDS ~60k cyc/CU vs
// VALU 16.4k/SIMD). New lane map: lane = n + 32*eh; each wave owns 8 WHOLE
// batch rows -> x is wave-uniform -> scalar loads (s_load, scalar cache,
// SGPR operand of v_fmac) -> zero x LDS traffic. Softmax over n = lane bits
// 0..4 -> fully in-wave, no wsum LDS. W padded LDS dbuf (reg-staged, 16B/ln);
// each W b128 feeds 8 rows. One barrier/ii (dbuf swap only). VGPR ~190
// (sacc 64 + wr 64 + gw 16 + per-row v), launch_bounds(256,2), 2 blocks/CU.

#define B_TOT 64
#define I_TOT 2048
#define NC    32
#define EV    16
#define OD    (NC*EV)      // 512
#define BC    32           // batch rows per block (4 waves x 8 rows)
#define RPW   8            // rows per wave
#define ICH   8            // i's per block
#define NIC   (I_TOT/ICH)  // 256
#define WPAD  132          // padded floats per capsule row (128 + 4)
#define WTILE (NC*WPAD)    // 4224 floats per i-tile

__device__ __forceinline__ void fma4(float4& acc, float a, const float4& w) {
    acc.x = fmaf(a, w.x, acc.x);
    acc.y = fmaf(a, w.y, acc.y);
    acc.z = fmaf(a, w.z, acc.z);
    acc.w = fmaf(a, w.w, acc.w);
}
__device__ __forceinline__ float dot4(const float4& a, const float4& b) {
    return a.x*b.x + a.y*b.y + a.z*b.z + a.w*b.w;
}

// MODE 0: c uniform (iter 0)          -> P partials
// MODE 1: a = u.vin, c = softmax(a)   -> P partials   (pass 1 AND pass 2)
template <int MODE>
__global__ __launch_bounds__(256, 2)
void route_pass(const float* __restrict__ x, const float* __restrict__ W,
                float* __restrict__ P, const float* __restrict__ vin)
{
    __shared__ __align__(16) float Wl[2 * WTILE];   // 33.8 KB (dbuf, padded)

    const int t    = threadIdx.x;
    const int lane = t & 63;
    const int n    = lane & 31;    // capsule (lane bits 0..4)
    const int eh   = lane >> 5;    // e-half (8 e's per lane)
    const int w    = __builtin_amdgcn_readfirstlane(t >> 6);   // wave 0..3

    const int ic = blockIdx.x & (NIC - 1);   // XCD = f(ic): bc-siblings share L2
    const int bc = blockIdx.x >> 8;          // 0..1
    const int b0 = bc * BC;
    const int i0 = ic * ICH;
    const int r0 = b0 + w * RPW;             // wave-uniform first row

    // ---- stage W tile 0 into padded LDS rows ----
    #pragma unroll
    for (int k = 0; k < 4; ++k) {
        const int g = (t + 256 * k) * 4;     // float idx 0..4092
        *(float4*)&Wl[(g >> 7) * WPAD + (g & 127)] =
            *(const float4*)&W[(size_t)i0 * 4096 + g];
    }
    __syncthreads();

    float4 sacc[RPW][2];
    #pragma unroll
    for (int r = 0; r < RPW; ++r) {
        sacc[r][0] = make_float4(0.f, 0.f, 0.f, 0.f);
        sacc[r][1] = make_float4(0.f, 0.f, 0.f, 0.f);
    }

    const int vbase = n * EV + eh * 8;

    #pragma unroll 1
    for (int ii = 0; ii < ICH; ++ii) {
        const int cur = (ii & 1) ? WTILE : 0;
        const int nxt = cur ^ WTILE;
        const bool pf = (ii + 1 < ICH);

        // ---- prefetch next W tile into registers (covered by row loop) ----
        float4 gw[4];
        if (pf) {
            #pragma unroll
            for (int k = 0; k < 4; ++k)
                gw[k] = *(const float4*)&W[(size_t)(i0 + ii + 1) * 4096 + (t + 256 * k) * 4];
        }

        // ---- this lane's W fragment: 8 d x 8 e = 16 float4 (reused by 8 rows) ----
        float4 wr[8][2];
        {
            const float* Wc = &Wl[cur + n * WPAD + eh * 8];
            #pragma unroll
            for (int d = 0; d < 8; ++d) {
                wr[d][0] = *(const float4*)&Wc[d * 16];
                wr[d][1] = *(const float4*)&Wc[d * 16 + 4];
            }
        }

        #pragma unroll
        for (int r = 0; r < RPW; ++r) {
            // x row: wave-uniform -> scalar loads, SGPR fmac operands
            const int xoff = __builtin_amdgcn_readfirstlane(
                ((r0 + r) * I_TOT + (i0 + ii)) * 8);
            const float4 xa = *(const float4*)&x[xoff];
            const float4 xb = *(const float4*)&x[xoff + 4];

            float4 u0 = make_float4(0.f, 0.f, 0.f, 0.f);
            float4 u1 = make_float4(0.f, 0.f, 0.f, 0.f);
            fma4(u0, xa.x, wr[0][0]); fma4(u1, xa.x, wr[0][1]);
            fma4(u0, xa.y, wr[1][0]); fma4(u1, xa.y, wr[1][1]);
            fma4(u0, xa.z, wr[2][0]); fma4(u1, xa.z, wr[2][1]);
            fma4(u0, xa.w, wr[3][0]); fma4(u1, xa.w, wr[3][1]);
            fma4(u0, xb.x, wr[4][0]); fma4(u1, xb.x, wr[4][1]);
            fma4(u0, xb.y, wr[5][0]); fma4(u1, xb.y, wr[5][1]);
            fma4(u0, xb.z, wr[6][0]); fma4(u1, xb.z, wr[6][1]);
            fma4(u0, xb.w, wr[7][0]); fma4(u1, xb.w, wr[7][1]);

            if (MODE == 0) {
                sacc[r][0].x += u0.x; sacc[r][0].y += u0.y;
                sacc[r][0].z += u0.z; sacc[r][0].w += u0.w;
                sacc[r][1].x += u1.x; sacc[r][1].y += u1.y;
                sacc[r][1].z += u1.z; sacc[r][1].w += u1.w;
            } else {
                const float* vp = &vin[(size_t)(r0 + r) * OD + vbase];
                const float4 v0 = *(const float4*)vp;
                const float4 v1 = *(const float4*)(vp + 4);
                // logit: 8-e partial in-lane, full 16-e via xor32
                float ap = dot4(u0, v0) + dot4(u1, v1);
                ap += __shfl_xor(ap, 32);
                const float e = __expf(ap);
                // softmax denominator over 32 capsules: all in-wave (bits 0..4)
                float p = e;
                p += __shfl_xor(p, 1);
                p += __shfl_xor(p, 2);
                p += __shfl_xor(p, 4);
                p += __shfl_xor(p, 8);
                p += __shfl_xor(p, 16);
                const float c = e * __builtin_amdgcn_rcpf(p);
                fma4(sacc[r][0], c, u0);
                fma4(sacc[r][1], c, u1);
            }
        }

        // ---- store prefetched tile into the other LDS buffer ----
        if (pf) {
            #pragma unroll
            for (int k = 0; k < 4; ++k) {
                const int g = (t + 256 * k) * 4;
                *(float4*)&Wl[nxt + (g >> 7) * WPAD + (g & 127)] = gw[k];
            }
        }
        __syncthreads();   // the ONLY barrier per ii (protects the dbuf swap)
    }

    // ---- partials: P[ic][b][o] (coalesced float4 pairs) ----
    #pragma unroll
    for (int r = 0; r < RPW; ++r) {
        float* dst = &P[((size_t)ic * B_TOT + r0 + r) * OD + vbase];
        *(float4*)dst       = sacc[r][0];
        *(float4*)(dst + 4) = sacc[r][1];
    }
}

// Reduce partials over NIC chunks + squash. grid = 64 b x 8 o-groups, 64 thr.
// dst[b*512+o] = squash(pre * sum_ic P)[o] + (addv ? addv[b*512+o] : 0)
__global__ __launch_bounds__(64)
void reduce_squash(const float* __restrict__ P, float* __restrict__ dst,
                   float pre, const float* __restrict__ addv)
{
    const int b = blockIdx.x >> 3, og = blockIdx.x & 7, t = threadIdx.x;
    const int o = og * 64 + t;
    float s0 = 0.f, s1 = 0.f, s2 = 0.f, s3 = 0.f;
    float s4 = 0.f, s5 = 0.f, s6 = 0.f, s7 = 0.f;
    for (int ic = 0; ic < NIC; ic += 8) {
        s0 += P[((size_t)(ic + 0) * B_TOT + b) * OD + o];
        s1 += P[((size_t)(ic + 1) * B_TOT + b) * OD + o];
        s2 += P[((size_t)(ic + 2) * B_TOT + b) * OD + o];
        s3 += P[((size_t)(ic + 3) * B_TOT + b) * OD + o];
        s4 += P[((size_t)(ic + 4) * B_TOT + b) * OD + o];
        s5 += P[((size_t)(ic + 5) * B_TOT + b) * OD + o];
        s6 += P[((size_t)(ic + 6) * B_TOT + b) * OD + o];
        s7 += P[((size_t)(ic + 7) * B_TOT + b) * OD + o];
    }
    float s = (((s0 + s1) + (s2 + s3)) + ((s4 + s5) + (s6 + s7))) * pre;
    // squared norm over e (o = n*16 + e; e bits are t&15)
    float q = s * s;
    q += __shfl_xor(q, 1);
    q += __shfl_xor(q, 2);
    q += __shfl_xor(q, 4);
    q += __shfl_xor(q, 8);
    float sc = q / ((1.0f + q) * sqrtf(q));
    float r = s * sc;
    if (addv) r += addv[(size_t)b * OD + o];
    dst[(size_t)b * OD + o] = r;
}

extern "C" void kernel_launch(void* const* d_in, const int* in_sizes, int n_in,
                              void* d_out, int out_size, void* d_ws, size_t ws_size,
                              hipStream_t stream) {
    const float* x = (const float*)d_in[0];
    const float* W = (const float*)d_in[1];
    float* out = (float*)d_out;

    char* ws = (char*)d_ws;
    float* P    = (float*)ws;                               // 256*64*512*4 = 32 MB
    float* v0   = (float*)(ws + (size_t)32 * 1024 * 1024);  // 128 KB
    float* vsum = v0 + B_TOT * OD;                          // 128 KB

    dim3 grid(2 * NIC), blk(256);   // 512 blocks = 2 per CU

    // pass 0: c uniform (1/32 folded into reduce pre-scale) -> v0
    route_pass<0><<<grid, blk, 0, stream>>>(x, W, P, nullptr);
    reduce_squash<<<B_TOT * 8, 64, 0, stream>>>(P, v0, 1.0f / 32.0f, nullptr);
    // pass 1: c = softmax(u.v0) -> v1; write vsum = v0 + v1
    route_pass<1><<<grid, blk, 0, stream>>>(x, W, P, v0);
    reduce_squash<<<B_TOT * 8, 64, 0, stream>>>(P, vsum, 1.0f, v0);
    // pass 2: logits = u.v0 + u.v1 = u.(v0+v1); c = softmax -> out
    route_pass<1><<<grid, blk, 0, stream>>>(x, W, P, vsum);
    reduce_squash<<<B_TOT * 8, 64, 0, stream>>>(P, out, 1.0f, nullptr);
}